// Round 5
// baseline (152.501 us; speedup 1.0000x reference)
//
#include <hip/hip_runtime.h>

#define NT 2000000
#define NE 20000
#define NTILES (NT / 64)   // 31250, exact

using bf16x8 = __attribute__((ext_vector_type(8))) __bf16;
using bf16x4 = __attribute__((ext_vector_type(4))) __bf16;
using f32x4  = __attribute__((ext_vector_type(4))) float;
using f32x2  = __attribute__((ext_vector_type(2))) float;
using fvec4  = __attribute__((ext_vector_type(4))) float;

// hi/lo bf16 split of 8 consecutive f32 (for k2 precision)
__device__ __forceinline__ void load_bsplit(const float* __restrict__ p,
                                            bf16x8& hi, bf16x8& lo) {
    fvec4 a = *(const fvec4*)p;
    fvec4 b = *(const fvec4*)(p + 4);
#pragma unroll
    for (int e = 0; e < 4; e++) {
        float v  = a[e];
        __bf16 h = (__bf16)v;
        hi[e]    = h;
        lo[e]    = (__bf16)(v - (float)h);
        float v2  = b[e];
        __bf16 h2 = (__bf16)v2;
        hi[e + 4] = h2;
        lo[e + 4] = (__bf16)(v2 - (float)h2);
    }
}

// plain bf16 load of 8 consecutive f32
__device__ __forceinline__ bf16x8 load_bf8(const float* __restrict__ p) {
    fvec4 a = *(const fvec4*)p;
    fvec4 b = *(const fvec4*)(p + 4);
    bf16x8 r;
#pragma unroll
    for (int e = 0; e < 4; e++) {
        r[e]     = (__bf16)a[e];
        r[e + 4] = (__bf16)b[e];
    }
    return r;
}

// ---------------- K1: fused phi1 (2 layers) + jagged segment-sum ----------------
// (256,4) = 16 waves/CU. w0/b0 staged in LDS (saves 32 VGPRs); next-tile
// seg/values prefetched; 2-step butterfly reduce (3 shfl vs 8) ending with
// feature j == lane. History: full acc + forced 3 blk spilled 240MB (r2);
// (256,2) latency-bound 18% occ (r3); (256,3) half-tile 50us, VALUBusy 44% (r4).
__global__ __launch_bounds__(256, 4) void k1_phi1(
    const float* __restrict__ values, const int* __restrict__ seg,
    const float* __restrict__ w0, const float* __restrict__ b0,
    const float* __restrict__ w1, const float* __restrict__ b1,
    float* __restrict__ ev) {
    __shared__ __align__(16) float lw0[64];
    __shared__ __align__(16) float lb0[64];

    const int tid = threadIdx.x;
    const int w   = tid >> 6;
    const int l   = tid & 63;
    const int l15 = l & 15;
    const int l4  = l >> 4;

    if (tid < 64) {
        lw0[tid] = w0[tid];
        lb0[tid] = b0[tid];
    }

    // B fragments for W1 (bf16): lane holds col j=16jf+l15, k = 32kf+8*l4+e
    bf16x8 Bh[2][4];
#pragma unroll
    for (int kf = 0; kf < 2; kf++)
#pragma unroll
        for (int jf = 0; jf < 4; jf++)
            Bh[kf][jf] = load_bf8(w1 + (jf * 16 + l15) * 64 + kf * 32 + l4 * 8);

    float biasj[4];
#pragma unroll
    for (int jf = 0; jf < 4; jf++) biasj[jf] = b1[jf * 16 + l15];

    __syncthreads();

    // 2-step butterfly: combine 4 per-jf partials across the 4 l4-groups so
    // that lane l ends holding the full column sum of feature j == l.
    const bool bit0 = (l & 16) != 0;
    const bool bit1 = (l & 32) != 0;
    auto reduce4 = [&](const float sj[4]) -> float {
        float send01 = bit0 ? sj[0] : sj[1];
        float keep01 = bit0 ? sj[1] : sj[0];
        float c01 = keep01 + __shfl_xor(send01, 16);
        float send23 = bit0 ? sj[2] : sj[3];
        float keep23 = bit0 ? sj[3] : sj[2];
        float c23 = keep23 + __shfl_xor(send23, 16);
        float send = bit1 ? c01 : c23;
        float keep = bit1 ? c23 : c01;
        return keep + __shfl_xor(send, 32);
    };

    const int stride = gridDim.x * 4;
    int tile = blockIdx.x * 4 + w;

    // preload first tile (always valid: 4096 < NTILES)
    int s_cur = seg[tile * 64 + l];
    float vp[4];
#pragma unroll
    for (int pf = 0; pf < 4; pf++) vp[pf] = values[tile * 64 + pf * 16 + l15];

    while (tile < NTILES) {
        // ---- prefetch next tile (uniform guard) ----
        const int ntile = tile + stride;
        int s_nxt = 0;
        float vpn[4] = {0.f, 0.f, 0.f, 0.f};
        if (ntile < NTILES) {
            const int nb = ntile * 64;
            s_nxt = seg[nb + l];
#pragma unroll
            for (int pf = 0; pf < 4; pf++) vpn[pf] = values[nb + pf * 16 + l15];
        }

        const int prev = __shfl_up(s_cur, 1);
        const unsigned long long bmask = __ballot((l > 0) && (s_cur != prev));

#pragma unroll
        for (int q = 0; q < 2; q++) {               // half-tile: rows [32q,32q+32)
            f32x4 acc[2][4];
#pragma unroll
            for (int i = 0; i < 2; i++)
#pragma unroll
                for (int jf = 0; jf < 4; jf++)
#pragma unroll
                    for (int r = 0; r < 4; r++) acc[i][jf][r] = biasj[jf];

#pragma unroll
            for (int kf = 0; kf < 2; kf++) {
                // layer-1 weights from LDS (broadcast within l4-group)
                const float* wk = lw0 + kf * 32 + l4 * 8;
                const float* bk = lb0 + kf * 32 + l4 * 8;
                const fvec4 wa = *(const fvec4*)wk;
                const fvec4 wb = *(const fvec4*)(wk + 4);
                const fvec4 ba = *(const fvec4*)bk;
                const fvec4 bb = *(const fvec4*)(bk + 4);

                bf16x8 A[2];
#pragma unroll
                for (int i = 0; i < 2; i++) {       // pf = 2q+i
                    const float vq = vp[2 * q + i];
#pragma unroll
                    for (int e = 0; e < 4; e++) {
                        float h0 = fmaxf(fmaf(vq, wa[e], ba[e]), 0.f);
                        float h1 = fmaxf(fmaf(vq, wb[e], bb[e]), 0.f);
                        A[i][e]     = (__bf16)h0;
                        A[i][e + 4] = (__bf16)h1;
                    }
                }
#pragma unroll
                for (int i = 0; i < 2; i++)
#pragma unroll
                    for (int jf = 0; jf < 4; jf++)
                        acc[i][jf] = __builtin_amdgcn_mfma_f32_16x16x32_bf16(
                            A[i], Bh[kf][jf], acc[i][jf], 0, 0, 0);
            }

            // relu h2 in-register
#pragma unroll
            for (int i = 0; i < 2; i++)
#pragma unroll
                for (int jf = 0; jf < 4; jf++)
#pragma unroll
                    for (int r = 0; r < 4; r++)
                        acc[i][jf][r] = fmaxf(acc[i][jf][r], 0.f);

            // boundary mask restricted to this half; bit0 (= half start) cleared
            const unsigned int mq =
                (unsigned int)(bmask >> (q * 32)) & 0xFFFFFFFEu;

            if (mq == 0u) {
                // uniform half: column sums, one atomic per lane (feature j==l)
                const int sid = __builtin_amdgcn_readlane(s_cur, q * 32);
                float sj[4];
#pragma unroll
                for (int jf = 0; jf < 4; jf++) {
                    f32x4 t = acc[0][jf] + acc[1][jf];
                    sj[jf] = (t[0] + t[1]) + (t[2] + t[3]);
                }
                atomicAdd(ev + (size_t)sid * 64 + l, reduce4(sj));
            } else {
                // run loop over boundaries within the half (wave-uniform scalars)
                unsigned int m = mq;
                int start = 0;
                int sid   = __builtin_amdgcn_readlane(s_cur, q * 32);
                while (true) {
                    const int end = m ? (int)__builtin_ctz(m) : 32;
                    float sj[4] = {0.f, 0.f, 0.f, 0.f};
#pragma unroll
                    for (int i = 0; i < 2; i++)
#pragma unroll
                        for (int r = 0; r < 4; r++) {
                            const int rel = i * 16 + l4 * 4 + r;
                            const float pm = (rel >= start && rel < end) ? 1.f : 0.f;
#pragma unroll
                            for (int jf = 0; jf < 4; jf++)
                                sj[jf] = fmaf(acc[i][jf][r], pm, sj[jf]);
                        }
                    atomicAdd(ev + (size_t)sid * 64 + l, reduce4(sj));
                    if (!m) break;
                    start = end;
                    sid   = __builtin_amdgcn_readlane(s_cur, q * 32 + start);
                    m &= (m - 1);
                }
            }
        }

        // rotate prefetched state
        tile  = ntile;
        s_cur = s_nxt;
#pragma unroll
        for (int pf = 0; pf < 4; pf++) vp[pf] = vpn[pf];
    }
}

// ---------------- K2: rho1 + o1 + phi2 (5 fused 64x64 layers) + event-sum ----------------
// one wave per 64 events, 313 blocks -> fills more CUs
__global__ __launch_bounds__(64) void k2_events(
    const float* __restrict__ ev,
    const float* __restrict__ W0, const float* __restrict__ B0,
    const float* __restrict__ W1, const float* __restrict__ B1,
    const float* __restrict__ W2, const float* __restrict__ B2,
    const float* __restrict__ W3, const float* __restrict__ B3,
    const float* __restrict__ W4, const float* __restrict__ B4,
    float* __restrict__ s2) {
    __shared__ __align__(16) __bf16 xt[64 * 72];   // [e][k], stride 72
    const int l   = threadIdx.x;
    const int l15 = l & 15;
    const int l4  = l >> 4;
    const int ebase = blockIdx.x * 64;

    const float* Ws[5] = {W0, W1, W2, W3, W4};
    const float* Bs[5] = {B0, B1, B2, B3, B4};

    // A fragments from ev (layer-0 input), masked for e >= NE
    bf16x8 A[4][2];
#pragma unroll
    for (int pf = 0; pf < 4; pf++) {
        const int e = ebase + pf * 16 + l15;
#pragma unroll
        for (int kf = 0; kf < 2; kf++) {
            bf16x8 a;
            if (e < NE) {
                const float* p = ev + (size_t)e * 64 + kf * 32 + l4 * 8;
                fvec4 x = *(const fvec4*)p;
                fvec4 y = *(const fvec4*)(p + 4);
#pragma unroll
                for (int e2 = 0; e2 < 4; e2++) {
                    a[e2]     = (__bf16)x[e2];
                    a[e2 + 4] = (__bf16)y[e2];
                }
            } else {
#pragma unroll
                for (int e2 = 0; e2 < 8; e2++) a[e2] = (__bf16)0.f;
            }
            A[pf][kf] = a;
        }
    }

#pragma unroll
    for (int L = 0; L < 5; L++) {
        bf16x8 Bh[2][4], Bl[2][4];
#pragma unroll
        for (int kf = 0; kf < 2; kf++)
#pragma unroll
            for (int jf = 0; jf < 4; jf++)
                load_bsplit(Ws[L] + (jf * 16 + l15) * 64 + kf * 32 + l4 * 8,
                            Bh[kf][jf], Bl[kf][jf]);

        f32x4 acc[4][4];
#pragma unroll
        for (int jf = 0; jf < 4; jf++) {
            const float bj = Bs[L][jf * 16 + l15];
#pragma unroll
            for (int pf = 0; pf < 4; pf++)
#pragma unroll
                for (int r = 0; r < 4; r++) acc[pf][jf][r] = bj;
        }
#pragma unroll
        for (int kf = 0; kf < 2; kf++)
#pragma unroll
            for (int pf = 0; pf < 4; pf++)
#pragma unroll
                for (int jf = 0; jf < 4; jf++)
                    acc[pf][jf] = __builtin_amdgcn_mfma_f32_16x16x32_bf16(
                        A[pf][kf], Bh[kf][jf], acc[pf][jf], 0, 0, 0);
#pragma unroll
        for (int kf = 0; kf < 2; kf++)
#pragma unroll
            for (int pf = 0; pf < 4; pf++)
#pragma unroll
                for (int jf = 0; jf < 4; jf++)
                    acc[pf][jf] = __builtin_amdgcn_mfma_f32_16x16x32_bf16(
                        A[pf][kf], Bl[kf][jf], acc[pf][jf], 0, 0, 0);

        if (L < 4) {
            // relu -> LDS [e][j] bf16, then reload as next layer's A-frags
#pragma unroll
            for (int pf = 0; pf < 4; pf++)
#pragma unroll
                for (int jf = 0; jf < 4; jf++) {
                    const int j = jf * 16 + l15;
#pragma unroll
                    for (int r = 0; r < 4; r++)
                        xt[(pf * 16 + l4 * 4 + r) * 72 + j] =
                            (__bf16)fmaxf(acc[pf][jf][r], 0.f);
                }
#pragma unroll
            for (int pf = 0; pf < 4; pf++)
#pragma unroll
                for (int kf = 0; kf < 2; kf++)
                    A[pf][kf] = *(const bf16x8*)(xt + (pf * 16 + l15) * 72 +
                                                 kf * 32 + l4 * 8);
        } else {
            // final phi2 layer: relu, masked sum over events, atomic into s2
            float sj[4];
#pragma unroll
            for (int jf = 0; jf < 4; jf++) {
                float s = 0.f;
#pragma unroll
                for (int pf = 0; pf < 4; pf++)
#pragma unroll
                    for (int r = 0; r < 4; r++) {
                        const int e = ebase + pf * 16 + l4 * 4 + r;
                        float v = fmaxf(acc[pf][jf][r], 0.f);
                        s += (e < NE) ? v : 0.f;
                    }
                s += __shfl_xor(s, 16);
                s += __shfl_xor(s, 32);
                sj[jf] = s;
            }
            float v = (l4 == 0) ? sj[0] : (l4 == 1) ? sj[1]
                    : (l4 == 2) ? sj[2] : sj[3];
            atomicAdd(s2 + l, v);
        }
    }
}

// ---------------- K3: rho2 + output + log_softmax (tiny) ----------------
__global__ __launch_bounds__(64) void k3_final(
    const float* __restrict__ s2,
    const float* __restrict__ W0, const float* __restrict__ B0,
    const float* __restrict__ W1, const float* __restrict__ B1,
    const float* __restrict__ W2, const float* __restrict__ B2,
    float* __restrict__ out) {
    __shared__ __align__(16) float xb[64];
    __shared__ __align__(16) float yb[64];
    __shared__ float ob[10];
    const int l = threadIdx.x;

    xb[l] = s2[l];
    __syncthreads();

    float a = B0[l];
#pragma unroll
    for (int k = 0; k < 16; k++) {
        fvec4 wv = *(const fvec4*)(W0 + l * 64 + k * 4);
        fvec4 xv = *(const fvec4*)(xb + k * 4);
        a += wv[0] * xv[0] + wv[1] * xv[1] + wv[2] * xv[2] + wv[3] * xv[3];
    }
    yb[l] = fmaxf(a, 0.f);
    __syncthreads();

    float b_ = B1[l];
#pragma unroll
    for (int k = 0; k < 16; k++) {
        fvec4 wv = *(const fvec4*)(W1 + l * 64 + k * 4);
        fvec4 xv = *(const fvec4*)(yb + k * 4);
        b_ += wv[0] * xv[0] + wv[1] * xv[1] + wv[2] * xv[2] + wv[3] * xv[3];
    }
    __syncthreads();
    xb[l] = fmaxf(b_, 0.f);
    __syncthreads();

    if (l < 10) {
        float o = B2[l];
#pragma unroll
        for (int k = 0; k < 16; k++) {
            fvec4 wv = *(const fvec4*)(W2 + l * 64 + k * 4);
            fvec4 xv = *(const fvec4*)(xb + k * 4);
            o += wv[0] * xv[0] + wv[1] * xv[1] + wv[2] * xv[2] + wv[3] * xv[3];
        }
        ob[l] = o;
    }
    __syncthreads();
    if (l == 0) {
        float m = ob[0];
#pragma unroll
        for (int i = 1; i < 10; i++) m = fmaxf(m, ob[i]);
        float sum = 0.f;
#pragma unroll
        for (int i = 0; i < 10; i++) sum = sum + expf(ob[i] - m);
        float ls = logf(sum);
#pragma unroll
        for (int i = 0; i < 10; i++) out[i] = ob[i] - m - ls;
    }
}

extern "C" void kernel_launch(void* const* d_in, const int* in_sizes, int n_in,
                              void* d_out, int out_size, void* d_ws, size_t ws_size,
                              hipStream_t stream) {
    const float* values = (const float*)d_in[0];
    const int*   seg    = (const int*)d_in[1];
    const float* p1w0 = (const float*)d_in[2],  *p1b0 = (const float*)d_in[3];
    const float* p1w1 = (const float*)d_in[4],  *p1b1 = (const float*)d_in[5];
    const float* r1w0 = (const float*)d_in[6],  *r1b0 = (const float*)d_in[7];
    const float* r1w1 = (const float*)d_in[8],  *r1b1 = (const float*)d_in[9];
    const float* o1w  = (const float*)d_in[10], *o1b  = (const float*)d_in[11];
    const float* p2w0 = (const float*)d_in[12], *p2b0 = (const float*)d_in[13];
    const float* p2w1 = (const float*)d_in[14], *p2b1 = (const float*)d_in[15];
    const float* r2w0 = (const float*)d_in[16], *r2b0 = (const float*)d_in[17];
    const float* r2w1 = (const float*)d_in[18], *r2b1 = (const float*)d_in[19];
    const float* o2w  = (const float*)d_in[20], *o2b  = (const float*)d_in[21];

    float* ev = (float*)d_ws;                       // [NE][64] accumulators
    float* s2 = ev + (size_t)NE * 64;               // [64]

    hipMemsetAsync(d_ws, 0, (size_t)(NE * 64 + 64) * sizeof(float), stream);

    hipLaunchKernelGGL(k1_phi1, dim3(1024), dim3(256), 0, stream,
                       values, seg, p1w0, p1b0, p1w1, p1b1, ev);
    hipLaunchKernelGGL(k2_events, dim3((NE + 63) / 64), dim3(64), 0, stream,
                       ev, r1w0, r1b0, r1w1, r1b1, o1w, o1b,
                       p2w0, p2b0, p2w1, p2b1, s2);
    hipLaunchKernelGGL(k3_final, dim3(1), dim3(64), 0, stream,
                       s2, r2w0, r2b0, r2w1, r2b1, o2w, o2b, (float*)d_out);
}

// Round 6
// 73.682 us; speedup vs baseline: 2.0697x; 2.0697x over previous
//
#include <hip/hip_runtime.h>

#define NT 2000000
#define NE 20000
#define NTILES (NT / 64)   // 31250, exact

using bf16x8 = __attribute__((ext_vector_type(8))) __bf16;
using bf16x4 = __attribute__((ext_vector_type(4))) __bf16;
using f32x4  = __attribute__((ext_vector_type(4))) float;
using f32x2  = __attribute__((ext_vector_type(2))) float;
using fvec4  = __attribute__((ext_vector_type(4))) float;

// hi/lo bf16 split of 8 consecutive f32 (for k2 precision)
__device__ __forceinline__ void load_bsplit(const float* __restrict__ p,
                                            bf16x8& hi, bf16x8& lo) {
    fvec4 a = *(const fvec4*)p;
    fvec4 b = *(const fvec4*)(p + 4);
#pragma unroll
    for (int e = 0; e < 4; e++) {
        float v  = a[e];
        __bf16 h = (__bf16)v;
        hi[e]    = h;
        lo[e]    = (__bf16)(v - (float)h);
        float v2  = b[e];
        __bf16 h2 = (__bf16)v2;
        hi[e + 4] = h2;
        lo[e + 4] = (__bf16)(v2 - (float)h2);
    }
}

// plain bf16 load of 8 consecutive f32
__device__ __forceinline__ bf16x8 load_bf8(const float* __restrict__ p) {
    fvec4 a = *(const fvec4*)p;
    fvec4 b = *(const fvec4*)(p + 4);
    bf16x8 r;
#pragma unroll
    for (int e = 0; e < 4; e++) {
        r[e]     = (__bf16)a[e];
        r[e + 4] = (__bf16)b[e];
    }
    return r;
}

// ---------------- K1: fused phi1 (2 layers) + jagged segment-sum ----------------
// (256,3) is the proven no-spill point (r4: VGPR 80, FETCH 8MB, 50us).
// r2/(256,3)+full-tile-acc and r5/(256,4) both spilled catastrophically
// (>200MB scratch) -> occupancy must come from trimming live state.
// This round: bias as MFMA C-operand (kills 64 movs/tile), butterfly
// reduce (3 shfl vs 8), whole-tile-uniform single-atomic, tile prefetch.
__global__ __launch_bounds__(256, 3) void k1_phi1(
    const float* __restrict__ values, const int* __restrict__ seg,
    const float* __restrict__ w0, const float* __restrict__ b0,
    const float* __restrict__ w1, const float* __restrict__ b1,
    float* __restrict__ ev) {
    const int tid = threadIdx.x;
    const int w   = tid >> 6;
    const int l   = tid & 63;
    const int l15 = l & 15;
    const int l4  = l >> 4;

    // B fragments for W1 (bf16): lane holds col j=16jf+l15, k = 32kf+8*l4+e
    bf16x8 Bh[2][4];
#pragma unroll
    for (int kf = 0; kf < 2; kf++)
#pragma unroll
        for (int jf = 0; jf < 4; jf++)
            Bh[kf][jf] = load_bf8(w1 + (jf * 16 + l15) * 64 + kf * 32 + l4 * 8);

    // layer-1 weights (f32) as f32x2 pairs -> v_pk_fma_f32 in the A-build
    f32x2 w0p[2][4], b0p[2][4];
#pragma unroll
    for (int kf = 0; kf < 2; kf++) {
        const int kb = kf * 32 + l4 * 8;
#pragma unroll
        for (int e2 = 0; e2 < 4; e2++) {
            w0p[kf][e2] = *(const f32x2*)(w0 + kb + e2 * 2);
            b0p[kf][e2] = *(const f32x2*)(b0 + kb + e2 * 2);
        }
    }
    // bias as a ready-made C fragment (first MFMA's C operand, no acc init)
    f32x4 biasC[4];
#pragma unroll
    for (int jf = 0; jf < 4; jf++) {
        const float bj = b1[jf * 16 + l15];
#pragma unroll
        for (int r = 0; r < 4; r++) biasC[jf][r] = bj;
    }

    // 2-step butterfly: lane l ends holding full column sum of feature j==l
    const bool bit0 = (l & 16) != 0;
    const bool bit1 = (l & 32) != 0;
    auto reduce4 = [&](const float sj[4]) -> float {
        float send01 = bit0 ? sj[0] : sj[1];
        float keep01 = bit0 ? sj[1] : sj[0];
        float c01 = keep01 + __shfl_xor(send01, 16);
        float send23 = bit0 ? sj[2] : sj[3];
        float keep23 = bit0 ? sj[3] : sj[2];
        float c23 = keep23 + __shfl_xor(send23, 16);
        float send = bit1 ? c01 : c23;
        float keep = bit1 ? c23 : c01;
        return keep + __shfl_xor(send, 32);
    };

    const int stride = gridDim.x * 4;
    int tile = blockIdx.x * 4 + w;            // 8192 waves < NTILES: always valid

    int s_cur = seg[tile * 64 + l];
    float vp[4];
#pragma unroll
    for (int pf = 0; pf < 4; pf++) vp[pf] = values[tile * 64 + pf * 16 + l15];

    while (tile < NTILES) {
        // ---- prefetch next tile (uniform guard) ----
        const int ntile = tile + stride;
        int s_nxt = 0;
        float vpn[4] = {0.f, 0.f, 0.f, 0.f};
        if (ntile < NTILES) {
            const int nb = ntile * 64;
            s_nxt = seg[nb + l];
#pragma unroll
            for (int pf = 0; pf < 4; pf++) vpn[pf] = values[nb + pf * 16 + l15];
        }

        const int prev = __shfl_up(s_cur, 1);
        const unsigned long long bmask = __ballot((l > 0) && (s_cur != prev));
        const bool tile_uniform = (bmask == 0ULL);

        float sjT[4] = {0.f, 0.f, 0.f, 0.f};  // whole-tile-uniform accumulator

#pragma unroll
        for (int q = 0; q < 2; q++) {         // half-tile: rows [32q,32q+32)
            f32x4 acc[2][4];

            // ---- kf = 0: A-build, MFMA with biasC as C (no acc init) ----
            {
                bf16x8 A[2];
#pragma unroll
                for (int i = 0; i < 2; i++) {
                    const float vq = vp[2 * q + i];
                    const f32x2 vv = {vq, vq};
#pragma unroll
                    for (int e2 = 0; e2 < 4; e2++) {
                        f32x2 h = w0p[0][e2] * vv + b0p[0][e2];
                        A[i][2 * e2]     = (__bf16)fmaxf(h[0], 0.f);
                        A[i][2 * e2 + 1] = (__bf16)fmaxf(h[1], 0.f);
                    }
                }
#pragma unroll
                for (int i = 0; i < 2; i++)
#pragma unroll
                    for (int jf = 0; jf < 4; jf++)
                        acc[i][jf] = __builtin_amdgcn_mfma_f32_16x16x32_bf16(
                            A[i], Bh[0][jf], biasC[jf], 0, 0, 0);
            }
            // ---- kf = 1: accumulate ----
            {
                bf16x8 A[2];
#pragma unroll
                for (int i = 0; i < 2; i++) {
                    const float vq = vp[2 * q + i];
                    const f32x2 vv = {vq, vq};
#pragma unroll
                    for (int e2 = 0; e2 < 4; e2++) {
                        f32x2 h = w0p[1][e2] * vv + b0p[1][e2];
                        A[i][2 * e2]     = (__bf16)fmaxf(h[0], 0.f);
                        A[i][2 * e2 + 1] = (__bf16)fmaxf(h[1], 0.f);
                    }
                }
#pragma unroll
                for (int i = 0; i < 2; i++)
#pragma unroll
                    for (int jf = 0; jf < 4; jf++)
                        acc[i][jf] = __builtin_amdgcn_mfma_f32_16x16x32_bf16(
                            A[i], Bh[1][jf], acc[i][jf], 0, 0, 0);
            }

            // relu h2 in-register
#pragma unroll
            for (int i = 0; i < 2; i++)
#pragma unroll
                for (int jf = 0; jf < 4; jf++)
#pragma unroll
                    for (int r = 0; r < 4; r++)
                        acc[i][jf][r] = fmaxf(acc[i][jf][r], 0.f);

            if (tile_uniform) {
                // accumulate both halves; single butterfly+atomic after q==1
#pragma unroll
                for (int jf = 0; jf < 4; jf++) {
                    f32x4 t = acc[0][jf] + acc[1][jf];
                    sjT[jf] += (t[0] + t[1]) + (t[2] + t[3]);
                }
                if (q == 1) {
                    const int sid = __builtin_amdgcn_readlane(s_cur, 0);
                    atomicAdd(ev + (size_t)sid * 64 + l, reduce4(sjT));
                }
            } else {
                const unsigned int mq =
                    (unsigned int)(bmask >> (q * 32)) & 0xFFFFFFFEu;
                if (mq == 0u) {
                    // uniform half: column sums + butterfly, one atomic
                    const int sid = __builtin_amdgcn_readlane(s_cur, q * 32);
                    float sj[4];
#pragma unroll
                    for (int jf = 0; jf < 4; jf++) {
                        f32x4 t = acc[0][jf] + acc[1][jf];
                        sj[jf] = (t[0] + t[1]) + (t[2] + t[3]);
                    }
                    atomicAdd(ev + (size_t)sid * 64 + l, reduce4(sj));
                } else {
                    // run loop over boundaries within the half
                    unsigned int m = mq;
                    int start = 0;
                    int sid   = __builtin_amdgcn_readlane(s_cur, q * 32);
                    while (true) {
                        const int end = m ? (int)__builtin_ctz(m) : 32;
                        float sj[4] = {0.f, 0.f, 0.f, 0.f};
#pragma unroll
                        for (int i = 0; i < 2; i++)
#pragma unroll
                            for (int r = 0; r < 4; r++) {
                                const int rel = i * 16 + l4 * 4 + r;
                                const float pm =
                                    (rel >= start && rel < end) ? 1.f : 0.f;
#pragma unroll
                                for (int jf = 0; jf < 4; jf++)
                                    sj[jf] = fmaf(acc[i][jf][r], pm, sj[jf]);
                            }
                        atomicAdd(ev + (size_t)sid * 64 + l, reduce4(sj));
                        if (!m) break;
                        start = end;
                        sid   = __builtin_amdgcn_readlane(s_cur, q * 32 + start);
                        m &= (m - 1);
                    }
                }
            }
        }

        // rotate prefetched state
        tile  = ntile;
        s_cur = s_nxt;
#pragma unroll
        for (int pf = 0; pf < 4; pf++) vp[pf] = vpn[pf];
    }
}

// ---------------- K2: rho1 + o1 + phi2 (5 fused 64x64 layers) + event-sum ----------------
__global__ __launch_bounds__(64) void k2_events(
    const float* __restrict__ ev,
    const float* __restrict__ W0, const float* __restrict__ B0,
    const float* __restrict__ W1, const float* __restrict__ B1,
    const float* __restrict__ W2, const float* __restrict__ B2,
    const float* __restrict__ W3, const float* __restrict__ B3,
    const float* __restrict__ W4, const float* __restrict__ B4,
    float* __restrict__ s2) {
    __shared__ __align__(16) __bf16 xt[64 * 72];   // [e][k], stride 72
    const int l   = threadIdx.x;
    const int l15 = l & 15;
    const int l4  = l >> 4;
    const int ebase = blockIdx.x * 64;

    const float* Ws[5] = {W0, W1, W2, W3, W4};
    const float* Bs[5] = {B0, B1, B2, B3, B4};

    bf16x8 A[4][2];
#pragma unroll
    for (int pf = 0; pf < 4; pf++) {
        const int e = ebase + pf * 16 + l15;
#pragma unroll
        for (int kf = 0; kf < 2; kf++) {
            bf16x8 a;
            if (e < NE) {
                const float* p = ev + (size_t)e * 64 + kf * 32 + l4 * 8;
                fvec4 x = *(const fvec4*)p;
                fvec4 y = *(const fvec4*)(p + 4);
#pragma unroll
                for (int e2 = 0; e2 < 4; e2++) {
                    a[e2]     = (__bf16)x[e2];
                    a[e2 + 4] = (__bf16)y[e2];
                }
            } else {
#pragma unroll
                for (int e2 = 0; e2 < 8; e2++) a[e2] = (__bf16)0.f;
            }
            A[pf][kf] = a;
        }
    }

#pragma unroll
    for (int L = 0; L < 5; L++) {
        bf16x8 Bh[2][4], Bl[2][4];
#pragma unroll
        for (int kf = 0; kf < 2; kf++)
#pragma unroll
            for (int jf = 0; jf < 4; jf++)
                load_bsplit(Ws[L] + (jf * 16 + l15) * 64 + kf * 32 + l4 * 8,
                            Bh[kf][jf], Bl[kf][jf]);

        f32x4 acc[4][4];
#pragma unroll
        for (int jf = 0; jf < 4; jf++) {
            const float bj = Bs[L][jf * 16 + l15];
#pragma unroll
            for (int pf = 0; pf < 4; pf++)
#pragma unroll
                for (int r = 0; r < 4; r++) acc[pf][jf][r] = bj;
        }
#pragma unroll
        for (int kf = 0; kf < 2; kf++)
#pragma unroll
            for (int pf = 0; pf < 4; pf++)
#pragma unroll
                for (int jf = 0; jf < 4; jf++)
                    acc[pf][jf] = __builtin_amdgcn_mfma_f32_16x16x32_bf16(
                        A[pf][kf], Bh[kf][jf], acc[pf][jf], 0, 0, 0);
#pragma unroll
        for (int kf = 0; kf < 2; kf++)
#pragma unroll
            for (int pf = 0; pf < 4; pf++)
#pragma unroll
                for (int jf = 0; jf < 4; jf++)
                    acc[pf][jf] = __builtin_amdgcn_mfma_f32_16x16x32_bf16(
                        A[pf][kf], Bl[kf][jf], acc[pf][jf], 0, 0, 0);

        if (L < 4) {
#pragma unroll
            for (int pf = 0; pf < 4; pf++)
#pragma unroll
                for (int jf = 0; jf < 4; jf++) {
                    const int j = jf * 16 + l15;
#pragma unroll
                    for (int r = 0; r < 4; r++)
                        xt[(pf * 16 + l4 * 4 + r) * 72 + j] =
                            (__bf16)fmaxf(acc[pf][jf][r], 0.f);
                }
#pragma unroll
            for (int pf = 0; pf < 4; pf++)
#pragma unroll
                for (int kf = 0; kf < 2; kf++)
                    A[pf][kf] = *(const bf16x8*)(xt + (pf * 16 + l15) * 72 +
                                                 kf * 32 + l4 * 8);
        } else {
            float sj[4];
#pragma unroll
            for (int jf = 0; jf < 4; jf++) {
                float s = 0.f;
#pragma unroll
                for (int pf = 0; pf < 4; pf++)
#pragma unroll
                    for (int r = 0; r < 4; r++) {
                        const int e = ebase + pf * 16 + l4 * 4 + r;
                        float v = fmaxf(acc[pf][jf][r], 0.f);
                        s += (e < NE) ? v : 0.f;
                    }
                s += __shfl_xor(s, 16);
                s += __shfl_xor(s, 32);
                sj[jf] = s;
            }
            float v = (l4 == 0) ? sj[0] : (l4 == 1) ? sj[1]
                    : (l4 == 2) ? sj[2] : sj[3];
            atomicAdd(s2 + l, v);
        }
    }
}

// ---------------- K3: rho2 + output + log_softmax (tiny) ----------------
__global__ __launch_bounds__(64) void k3_final(
    const float* __restrict__ s2,
    const float* __restrict__ W0, const float* __restrict__ B0,
    const float* __restrict__ W1, const float* __restrict__ B1,
    const float* __restrict__ W2, const float* __restrict__ B2,
    float* __restrict__ out) {
    __shared__ __align__(16) float xb[64];
    __shared__ __align__(16) float yb[64];
    __shared__ float ob[10];
    const int l = threadIdx.x;

    xb[l] = s2[l];
    __syncthreads();

    float a = B0[l];
#pragma unroll
    for (int k = 0; k < 16; k++) {
        fvec4 wv = *(const fvec4*)(W0 + l * 64 + k * 4);
        fvec4 xv = *(const fvec4*)(xb + k * 4);
        a += wv[0] * xv[0] + wv[1] * xv[1] + wv[2] * xv[2] + wv[3] * xv[3];
    }
    yb[l] = fmaxf(a, 0.f);
    __syncthreads();

    float b_ = B1[l];
#pragma unroll
    for (int k = 0; k < 16; k++) {
        fvec4 wv = *(const fvec4*)(W1 + l * 64 + k * 4);
        fvec4 xv = *(const fvec4*)(yb + k * 4);
        b_ += wv[0] * xv[0] + wv[1] * xv[1] + wv[2] * xv[2] + wv[3] * xv[3];
    }
    __syncthreads();
    xb[l] = fmaxf(b_, 0.f);
    __syncthreads();

    if (l < 10) {
        float o = B2[l];
#pragma unroll
        for (int k = 0; k < 16; k++) {
            fvec4 wv = *(const fvec4*)(W2 + l * 64 + k * 4);
            fvec4 xv = *(const fvec4*)(xb + k * 4);
            o += wv[0] * xv[0] + wv[1] * xv[1] + wv[2] * xv[2] + wv[3] * xv[3];
        }
        ob[l] = o;
    }
    __syncthreads();
    if (l == 0) {
        float m = ob[0];
#pragma unroll
        for (int i = 1; i < 10; i++) m = fmaxf(m, ob[i]);
        float sum = 0.f;
#pragma unroll
        for (int i = 0; i < 10; i++) sum = sum + expf(ob[i] - m);
        float ls = logf(sum);
#pragma unroll
        for (int i = 0; i < 10; i++) out[i] = ob[i] - m - ls;
    }
}

extern "C" void kernel_launch(void* const* d_in, const int* in_sizes, int n_in,
                              void* d_out, int out_size, void* d_ws, size_t ws_size,
                              hipStream_t stream) {
    const float* values = (const float*)d_in[0];
    const int*   seg    = (const int*)d_in[1];
    const float* p1w0 = (const float*)d_in[2],  *p1b0 = (const float*)d_in[3];
    const float* p1w1 = (const float*)d_in[4],  *p1b1 = (const float*)d_in[5];
    const float* r1w0 = (const float*)d_in[6],  *r1b0 = (const float*)d_in[7];
    const float* r1w1 = (const float*)d_in[8],  *r1b1 = (const float*)d_in[9];
    const float* o1w  = (const float*)d_in[10], *o1b  = (const float*)d_in[11];
    const float* p2w0 = (const float*)d_in[12], *p2b0 = (const float*)d_in[13];
    const float* p2w1 = (const float*)d_in[14], *p2b1 = (const float*)d_in[15];
    const float* r2w0 = (const float*)d_in[16], *r2b0 = (const float*)d_in[17];
    const float* r2w1 = (const float*)d_in[18], *r2b1 = (const float*)d_in[19];
    const float* o2w  = (const float*)d_in[20], *o2b  = (const float*)d_in[21];

    float* ev = (float*)d_ws;                       // [NE][64] accumulators
    float* s2 = ev + (size_t)NE * 64;               // [64]

    hipMemsetAsync(d_ws, 0, (size_t)(NE * 64 + 64) * sizeof(float), stream);

    hipLaunchKernelGGL(k1_phi1, dim3(2048), dim3(256), 0, stream,
                       values, seg, p1w0, p1b0, p1w1, p1b1, ev);
    hipLaunchKernelGGL(k2_events, dim3((NE + 63) / 64), dim3(64), 0, stream,
                       ev, r1w0, r1b0, r1w1, r1b1, o1w, o1b,
                       p2w0, p2b0, p2w1, p2b1, s2);
    hipLaunchKernelGGL(k3_final, dim3(1), dim3(64), 0, stream,
                       s2, r2w0, r2b0, r2w1, r2b1, o2w, o2b, (float*)d_out);
}

// Round 7
// 73.649 us; speedup vs baseline: 2.0707x; 1.0004x over previous
//
#include <hip/hip_runtime.h>

#define NT 2000000
#define NE 20000
#define NTILES (NT / 64)   // 31250, exact

using bf16x8 = __attribute__((ext_vector_type(8))) __bf16;
using bf16x4 = __attribute__((ext_vector_type(4))) __bf16;
using f32x4  = __attribute__((ext_vector_type(4))) float;
using f32x2  = __attribute__((ext_vector_type(2))) float;
using fvec4  = __attribute__((ext_vector_type(4))) float;

// hi/lo bf16 split of 8 consecutive f32 (for k2 precision)
__device__ __forceinline__ void load_bsplit(const float* __restrict__ p,
                                            bf16x8& hi, bf16x8& lo) {
    fvec4 a = *(const fvec4*)p;
    fvec4 b = *(const fvec4*)(p + 4);
#pragma unroll
    for (int e = 0; e < 4; e++) {
        float v  = a[e];
        __bf16 h = (__bf16)v;
        hi[e]    = h;
        lo[e]    = (__bf16)(v - (float)h);
        float v2  = b[e];
        __bf16 h2 = (__bf16)v2;
        hi[e + 4] = h2;
        lo[e + 4] = (__bf16)(v2 - (float)h2);
    }
}

// plain bf16 load of 8 consecutive f32
__device__ __forceinline__ bf16x8 load_bf8(const float* __restrict__ p) {
    fvec4 a = *(const fvec4*)p;
    fvec4 b = *(const fvec4*)(p + 4);
    bf16x8 r;
#pragma unroll
    for (int e = 0; e < 4; e++) {
        r[e]     = (__bf16)a[e];
        r[e + 4] = (__bf16)b[e];
    }
    return r;
}

// ---------------- K1: fused phi1 (2 layers) + jagged segment-sum ----------------
// STREAMING REDUCE: per 16-row block, the 2-MFMA chain's output is relu'd and
// folded into 4 running per-feature partials immediately -> no 64-reg acc tile.
// Live state ~110 regs -> (256,4) = 16 waves/CU without the r5 spill (r5's
// (256,4) + 64-reg acc split 64/64 and spilled 226MB; r2's (256,3) + full acc
// spilled 240MB). Tripwire: FETCH_SIZE must stay ~8MB.
__global__ __launch_bounds__(256, 4) void k1_phi1(
    const float* __restrict__ values, const int* __restrict__ seg,
    const float* __restrict__ w0, const float* __restrict__ b0,
    const float* __restrict__ w1, const float* __restrict__ b1,
    float* __restrict__ ev) {
    const int tid = threadIdx.x;
    const int w   = tid >> 6;
    const int l   = tid & 63;
    const int l15 = l & 15;
    const int l4  = l >> 4;

    // B fragments for W1 (bf16): lane holds col j=16jf+l15, k = 32kf+8*l4+e
    bf16x8 Bh[2][4];
#pragma unroll
    for (int kf = 0; kf < 2; kf++)
#pragma unroll
        for (int jf = 0; jf < 4; jf++)
            Bh[kf][jf] = load_bf8(w1 + (jf * 16 + l15) * 64 + kf * 32 + l4 * 8);

    // layer-1 weights (f32) as f32x2 pairs -> v_pk_fma_f32 in the A-build
    f32x2 w0p[2][4], b0p[2][4];
#pragma unroll
    for (int kf = 0; kf < 2; kf++) {
        const int kb = kf * 32 + l4 * 8;
#pragma unroll
        for (int e2 = 0; e2 < 4; e2++) {
            w0p[kf][e2] = *(const f32x2*)(w0 + kb + e2 * 2);
            b0p[kf][e2] = *(const f32x2*)(b0 + kb + e2 * 2);
        }
    }
    // bias as a ready-made C fragment (first MFMA's C operand)
    f32x4 biasC[4];
#pragma unroll
    for (int jf = 0; jf < 4; jf++) {
        const float bj = b1[jf * 16 + l15];
#pragma unroll
        for (int r = 0; r < 4; r++) biasC[jf][r] = bj;
    }

    // 2-step butterfly: lane l ends holding full column sum of feature j==l
    const bool bit0 = (l & 16) != 0;
    const bool bit1 = (l & 32) != 0;
    auto reduce4 = [&](const float sj[4]) -> float {
        float send01 = bit0 ? sj[0] : sj[1];
        float keep01 = bit0 ? sj[1] : sj[0];
        float c01 = keep01 + __shfl_xor(send01, 16);
        float send23 = bit0 ? sj[2] : sj[3];
        float keep23 = bit0 ? sj[3] : sj[2];
        float c23 = keep23 + __shfl_xor(send23, 16);
        float send = bit1 ? c01 : c23;
        float keep = bit1 ? c23 : c01;
        return keep + __shfl_xor(send, 32);
    };

    const int stride = gridDim.x * 4;             // 1024 blocks -> 4096
    int tile = blockIdx.x * 4 + w;                // < 4096 <= NTILES: valid

    int s_cur = seg[tile * 64 + l];
    float vp[4];
#pragma unroll
    for (int pf = 0; pf < 4; pf++) vp[pf] = values[tile * 64 + pf * 16 + l15];

    while (tile < NTILES) {
        // ---- prefetch next tile (uniform guard) ----
        const int ntile = tile + stride;
        int s_nxt = 0;
        float vpn[4] = {0.f, 0.f, 0.f, 0.f};
        if (ntile < NTILES) {
            const int nb = ntile * 64;
            s_nxt = seg[nb + l];
#pragma unroll
            for (int pf = 0; pf < 4; pf++) vpn[pf] = values[nb + pf * 16 + l15];
        }

        const int prev = __shfl_up(s_cur, 1);
        const unsigned long long bmask = __ballot((l > 0) && (s_cur != prev));

        int   cur = __builtin_amdgcn_readlane(s_cur, 0);
        float sj[4] = {0.f, 0.f, 0.f, 0.f};

#pragma unroll
        for (int q = 0; q < 2; q++) {
#pragma unroll
            for (int i = 0; i < 2; i++) {         // 16-row block, B = q*32+i*16
                const int B = q * 32 + i * 16;
                const float vq = vp[2 * q + i];
                const f32x2 vv = {vq, vq};

                // A fragments for both kf (h1 = relu(v*w0+b0), f32 math)
                bf16x8 A0, A1;
#pragma unroll
                for (int e2 = 0; e2 < 4; e2++) {
                    f32x2 h0 = w0p[0][e2] * vv + b0p[0][e2];   // v_pk_fma_f32
                    A0[2 * e2]     = (__bf16)fmaxf(h0[0], 0.f);
                    A0[2 * e2 + 1] = (__bf16)fmaxf(h0[1], 0.f);
                    f32x2 h1 = w0p[1][e2] * vv + b0p[1][e2];
                    A1[2 * e2]     = (__bf16)fmaxf(h1[0], 0.f);
                    A1[2 * e2 + 1] = (__bf16)fmaxf(h1[1], 0.f);
                }

                // 2-MFMA chain per jf, relu'd into frag (streaming, no acc tile)
                f32x4 frag[4];
#pragma unroll
                for (int jf = 0; jf < 4; jf++) {
                    f32x4 t = __builtin_amdgcn_mfma_f32_16x16x32_bf16(
                        A0, Bh[0][jf], biasC[jf], 0, 0, 0);
                    t = __builtin_amdgcn_mfma_f32_16x16x32_bf16(
                        A1, Bh[1][jf], t, 0, 0, 0);
#pragma unroll
                    for (int r = 0; r < 4; r++) frag[jf][r] = fmaxf(t[r], 0.f);
                }

                // fold into running per-jf partials, honoring seg boundaries
                const unsigned int mb =
                    (unsigned int)((bmask >> B) & 0xFFFFull);
                if (mb == 0u) {
#pragma unroll
                    for (int jf = 0; jf < 4; jf++)
                        sj[jf] += (frag[jf][0] + frag[jf][1]) +
                                  (frag[jf][2] + frag[jf][3]);
                } else {
                    unsigned int m = mb;
                    int start = 0;
                    while (true) {
                        const int e = m ? (int)__builtin_ctz(m) : 16;
#pragma unroll
                        for (int jf = 0; jf < 4; jf++) {
                            float s = 0.f;
#pragma unroll
                            for (int r = 0; r < 4; r++) {
                                const int rel = l4 * 4 + r;
                                s += (rel >= start && rel < e) ? frag[jf][r]
                                                               : 0.f;
                            }
                            sj[jf] += s;
                        }
                        if (!m) break;
                        // boundary at block-rel e: flush current event
                        atomicAdd(ev + (size_t)cur * 64 + l, reduce4(sj));
                        sj[0] = sj[1] = sj[2] = sj[3] = 0.f;
                        cur   = __builtin_amdgcn_readlane(s_cur, B + e);
                        start = e;
                        m &= (m - 1);
                    }
                }
            }
        }
        // tile-end flush
        atomicAdd(ev + (size_t)cur * 64 + l, reduce4(sj));

        // rotate prefetched state
        tile  = ntile;
        s_cur = s_nxt;
#pragma unroll
        for (int pf = 0; pf < 4; pf++) vp[pf] = vpn[pf];
    }
}

// ---------------- K2: rho1 + o1 + phi2 (5 fused 64x64 layers) + event-sum ----------------
__global__ __launch_bounds__(64) void k2_events(
    const float* __restrict__ ev,
    const float* __restrict__ W0, const float* __restrict__ B0,
    const float* __restrict__ W1, const float* __restrict__ B1,
    const float* __restrict__ W2, const float* __restrict__ B2,
    const float* __restrict__ W3, const float* __restrict__ B3,
    const float* __restrict__ W4, const float* __restrict__ B4,
    float* __restrict__ s2) {
    __shared__ __align__(16) __bf16 xt[64 * 72];   // [e][k], stride 72
    const int l   = threadIdx.x;
    const int l15 = l & 15;
    const int l4  = l >> 4;
    const int ebase = blockIdx.x * 64;

    const float* Ws[5] = {W0, W1, W2, W3, W4};
    const float* Bs[5] = {B0, B1, B2, B3, B4};

    bf16x8 A[4][2];
#pragma unroll
    for (int pf = 0; pf < 4; pf++) {
        const int e = ebase + pf * 16 + l15;
#pragma unroll
        for (int kf = 0; kf < 2; kf++) {
            bf16x8 a;
            if (e < NE) {
                const float* p = ev + (size_t)e * 64 + kf * 32 + l4 * 8;
                fvec4 x = *(const fvec4*)p;
                fvec4 y = *(const fvec4*)(p + 4);
#pragma unroll
                for (int e2 = 0; e2 < 4; e2++) {
                    a[e2]     = (__bf16)x[e2];
                    a[e2 + 4] = (__bf16)y[e2];
                }
            } else {
#pragma unroll
                for (int e2 = 0; e2 < 8; e2++) a[e2] = (__bf16)0.f;
            }
            A[pf][kf] = a;
        }
    }

#pragma unroll
    for (int L = 0; L < 5; L++) {
        bf16x8 Bh[2][4], Bl[2][4];
#pragma unroll
        for (int kf = 0; kf < 2; kf++)
#pragma unroll
            for (int jf = 0; jf < 4; jf++)
                load_bsplit(Ws[L] + (jf * 16 + l15) * 64 + kf * 32 + l4 * 8,
                            Bh[kf][jf], Bl[kf][jf]);

        f32x4 acc[4][4];
#pragma unroll
        for (int jf = 0; jf < 4; jf++) {
            const float bj = Bs[L][jf * 16 + l15];
#pragma unroll
            for (int pf = 0; pf < 4; pf++)
#pragma unroll
                for (int r = 0; r < 4; r++) acc[pf][jf][r] = bj;
        }
#pragma unroll
        for (int kf = 0; kf < 2; kf++)
#pragma unroll
            for (int pf = 0; pf < 4; pf++)
#pragma unroll
                for (int jf = 0; jf < 4; jf++)
                    acc[pf][jf] = __builtin_amdgcn_mfma_f32_16x16x32_bf16(
                        A[pf][kf], Bh[kf][jf], acc[pf][jf], 0, 0, 0);
#pragma unroll
        for (int kf = 0; kf < 2; kf++)
#pragma unroll
            for (int pf = 0; pf < 4; pf++)
#pragma unroll
                for (int jf = 0; jf < 4; jf++)
                    acc[pf][jf] = __builtin_amdgcn_mfma_f32_16x16x32_bf16(
                        A[pf][kf], Bl[kf][jf], acc[pf][jf], 0, 0, 0);

        if (L < 4) {
#pragma unroll
            for (int pf = 0; pf < 4; pf++)
#pragma unroll
                for (int jf = 0; jf < 4; jf++) {
                    const int j = jf * 16 + l15;
#pragma unroll
                    for (int r = 0; r < 4; r++)
                        xt[(pf * 16 + l4 * 4 + r) * 72 + j] =
                            (__bf16)fmaxf(acc[pf][jf][r], 0.f);
                }
#pragma unroll
            for (int pf = 0; pf < 4; pf++)
#pragma unroll
                for (int kf = 0; kf < 2; kf++)
                    A[pf][kf] = *(const bf16x8*)(xt + (pf * 16 + l15) * 72 +
                                                 kf * 32 + l4 * 8);
        } else {
            float sj[4];
#pragma unroll
            for (int jf = 0; jf < 4; jf++) {
                float s = 0.f;
#pragma unroll
                for (int pf = 0; pf < 4; pf++)
#pragma unroll
                    for (int r = 0; r < 4; r++) {
                        const int e = ebase + pf * 16 + l4 * 4 + r;
                        float v = fmaxf(acc[pf][jf][r], 0.f);
                        s += (e < NE) ? v : 0.f;
                    }
                s += __shfl_xor(s, 16);
                s += __shfl_xor(s, 32);
                sj[jf] = s;
            }
            float v = (l4 == 0) ? sj[0] : (l4 == 1) ? sj[1]
                    : (l4 == 2) ? sj[2] : sj[3];
            atomicAdd(s2 + l, v);
        }
    }
}

// ---------------- K3: rho2 + output + log_softmax (tiny) ----------------
__global__ __launch_bounds__(64) void k3_final(
    const float* __restrict__ s2,
    const float* __restrict__ W0, const float* __restrict__ B0,
    const float* __restrict__ W1, const float* __restrict__ B1,
    const float* __restrict__ W2, const float* __restrict__ B2,
    float* __restrict__ out) {
    __shared__ __align__(16) float xb[64];
    __shared__ __align__(16) float yb[64];
    __shared__ float ob[10];
    const int l = threadIdx.x;

    xb[l] = s2[l];
    __syncthreads();

    float a = B0[l];
#pragma unroll
    for (int k = 0; k < 16; k++) {
        fvec4 wv = *(const fvec4*)(W0 + l * 64 + k * 4);
        fvec4 xv = *(const fvec4*)(xb + k * 4);
        a += wv[0] * xv[0] + wv[1] * xv[1] + wv[2] * xv[2] + wv[3] * xv[3];
    }
    yb[l] = fmaxf(a, 0.f);
    __syncthreads();

    float b_ = B1[l];
#pragma unroll
    for (int k = 0; k < 16; k++) {
        fvec4 wv = *(const fvec4*)(W1 + l * 64 + k * 4);
        fvec4 xv = *(const fvec4*)(yb + k * 4);
        b_ += wv[0] * xv[0] + wv[1] * xv[1] + wv[2] * xv[2] + wv[3] * xv[3];
    }
    __syncthreads();
    xb[l] = fmaxf(b_, 0.f);
    __syncthreads();

    if (l < 10) {
        float o = B2[l];
#pragma unroll
        for (int k = 0; k < 16; k++) {
            fvec4 wv = *(const fvec4*)(W2 + l * 64 + k * 4);
            fvec4 xv = *(const fvec4*)(xb + k * 4);
            o += wv[0] * xv[0] + wv[1] * xv[1] + wv[2] * xv[2] + wv[3] * xv[3];
        }
        ob[l] = o;
    }
    __syncthreads();
    if (l == 0) {
        float m = ob[0];
#pragma unroll
        for (int i = 1; i < 10; i++) m = fmaxf(m, ob[i]);
        float sum = 0.f;
#pragma unroll
        for (int i = 0; i < 10; i++) sum = sum + expf(ob[i] - m);
        float ls = logf(sum);
#pragma unroll
        for (int i = 0; i < 10; i++) out[i] = ob[i] - m - ls;
    }
}

extern "C" void kernel_launch(void* const* d_in, const int* in_sizes, int n_in,
                              void* d_out, int out_size, void* d_ws, size_t ws_size,
                              hipStream_t stream) {
    const float* values = (const float*)d_in[0];
    const int*   seg    = (const int*)d_in[1];
    const float* p1w0 = (const float*)d_in[2],  *p1b0 = (const float*)d_in[3];
    const float* p1w1 = (const float*)d_in[4],  *p1b1 = (const float*)d_in[5];
    const float* r1w0 = (const float*)d_in[6],  *r1b0 = (const float*)d_in[7];
    const float* r1w1 = (const float*)d_in[8],  *r1b1 = (const float*)d_in[9];
    const float* o1w  = (const float*)d_in[10], *o1b  = (const float*)d_in[11];
    const float* p2w0 = (const float*)d_in[12], *p2b0 = (const float*)d_in[13];
    const float* p2w1 = (const float*)d_in[14], *p2b1 = (const float*)d_in[15];
    const float* r2w0 = (const float*)d_in[16], *r2b0 = (const float*)d_in[17];
    const float* r2w1 = (const float*)d_in[18], *r2b1 = (const float*)d_in[19];
    const float* o2w  = (const float*)d_in[20], *o2b  = (const float*)d_in[21];

    float* ev = (float*)d_ws;                       // [NE][64] accumulators
    float* s2 = ev + (size_t)NE * 64;               // [64]

    hipMemsetAsync(d_ws, 0, (size_t)(NE * 64 + 64) * sizeof(float), stream);

    hipLaunchKernelGGL(k1_phi1, dim3(1024), dim3(256), 0, stream,
                       values, seg, p1w0, p1b0, p1w1, p1b1, ev);
    hipLaunchKernelGGL(k2_events, dim3((NE + 63) / 64), dim3(64), 0, stream,
                       ev, r1w0, r1b0, r1w1, r1b1, o1w, o1b,
                       p2w0, p2b0, p2w1, p2b1, s2);
    hipLaunchKernelGGL(k3_final, dim3(1), dim3(64), 0, stream,
                       s2, r2w0, r2b0, r2w1, r2b1, o2w, o2b, (float*)d_out);
}